// Round 15
// baseline (883.653 us; speedup 1.0000x reference)
//
#include <hip/hip_runtime.h>
#include <math.h>

#define H_DIM 1024
#define SEG_LEN 18
#define N_SEG 32
#define QUOTA 9
#define GAP_THR 8.0e-4f

typedef _Float16 half8 __attribute__((ext_vector_type(8)));
typedef _Float16 half4 __attribute__((ext_vector_type(4)));
typedef float f32x4 __attribute__((ext_vector_type(4)));
typedef float f32x16 __attribute__((ext_vector_type(16)));

__device__ __forceinline__ void gload_lds16(const void* g, void* l) {
    __builtin_amdgcn_global_load_lds((const __attribute__((address_space(1))) uint32_t*)g,
                                     (__attribute__((address_space(3))) uint32_t*)l,
                                     16, 0, 0);
}

__device__ __forceinline__ float gelu_exact(float h) {
    return 0.5f * h * (1.0f + erff(h * 0.70710678118654752f));
}

// ---- pack W1 [512][1024] fp32 into two layouts ----
// B32 (2 MB): 32x32x16-frag order, 2 exact-split fp16 planes (recheck kernel).
// B16 (1 MB): 16x16x32-frag order, plane-0 only (screen kernel):
//   half-off = (ks*32 + nf16)*512 + lane*8 + j   (each frag = 1 KB contiguous)
__global__ void pack_w1_kernel(const float* __restrict__ W1,
                               _Float16* __restrict__ B32,
                               _Float16* __restrict__ B16) {
    const int bid = blockIdx.x, t = threadIdx.x;
    if (bid < 256) {
        int tid = bid * 256 + t;
        int q = tid & 127, n = tid >> 7;
        int kt = q >> 2, ksub = (q >> 1) & 1, hi = q & 1;
        int nb = n >> 8, nf = (n >> 5) & 7, nlo = n & 31;
        const float* src = W1 + (size_t)n * H_DIM + q * 8;
        float4 v0 = *(const float4*)src, v1 = *(const float4*)(src + 4);
        float xs[8] = {v0.x, v0.y, v0.z, v0.w, v1.x, v1.y, v1.z, v1.w};
        half8 h0, h1;
#pragma unroll
        for (int j = 0; j < 8; ++j) {
            _Float16 a = (_Float16)xs[j];
            float r = xs[j] - (float)a;
            h0[j] = a;
            h1[j] = (_Float16)(r * 2048.0f);
        }
        size_t base = (size_t)kt * 32768 + nb * 16384 + ksub * 4096 + nf * 512
                    + (size_t)(hi * 32 + nlo) * 8;
        *(half8*)(B32 + base) = h0;
        *(half8*)(B32 + base + 8192) = h1;
    } else {
        int tid = (bid - 256) * 256 + t;
        int lane = tid & 63, nf = (tid >> 6) & 31, ks = tid >> 11;
        int n = nf * 16 + (lane & 15), k0 = ks * 32 + (lane >> 4) * 8;
        const float* src = W1 + (size_t)n * H_DIM + k0;
        float4 v0 = *(const float4*)src, v1 = *(const float4*)(src + 4);
        float xs[8] = {v0.x, v0.y, v0.z, v0.w, v1.x, v1.y, v1.z, v1.w};
        half8 h0;
#pragma unroll
        for (int j = 0; j < 8; ++j) h0[j] = (_Float16)xs[j];
        *(half8*)(B16 + ((size_t)(ks * 32 + nf)) * 512 + lane * 8) = h0;
    }
}

// ---- stage-1 scorer: merged-nb (64 rows x 512 cols, 8 waves of 64x64) ----
// A staged ONCE per block (was twice via nb-split): waves 0-3 keep R14's
// exact staging role (4-step 16 KB tiles, dbuf, one lgkm barrier per tile);
// waves 4-7 only consume. B direct from L2 in fragment order, 2-deep bank
// rotation. Wave-level math identical to R14 -> scores bit-identical.
__global__ __launch_bounds__(512, 4)
void stage1_kernel(const float* __restrict__ X, const _Float16* __restrict__ B16,
                   const float* __restrict__ b1, const float* __restrict__ W2,
                   float* __restrict__ scores) {
    __shared__ __align__(16) char smem[34816];  // A dbuf 2x16KB; red[8][64][17] overlays
    const int t = threadIdx.x;          // 0..511
    const int w = t >> 6, lane = t & 63;
    const size_t m0 = (size_t)blockIdx.x * 64;

    // A staging role (threads 0-255 = waves 0-3, R14 mapping verbatim)
    const int arow = (w & 3) * 16 + (t & 15);
    const int aq = (t >> 4) & 3;
    const float* aptr = X + (m0 + arow) * H_DIM + aq * 8;
    const int awoff = (w & 3) * 1024 + ((t & 15) + 16 * aq) * 16;
    // B direct: wave w covers cols w*64..w*64+63 -> frags w*4+j
    const _Float16* bptr = B16 + ((size_t)(w * 4)) * 512 + lane * 8;

    f32x4 acc[4][4] = {};
    float4 av[4][2];
    half8 bk0[4], bk1[4];

#define AV_LOAD(s, ks)                                                          \
    do {                                                                        \
        av[s][0] = *(const float4*)(aptr + (ks) * 32);                          \
        av[s][1] = *(const float4*)(aptr + (ks) * 32 + 4);                      \
    } while (0)

#define AV_CVTW(s, base)                                                        \
    do {                                                                        \
        float4 u = av[s][0], v = av[s][1];                                      \
        half8 h_;                                                               \
        h_[0] = (_Float16)u.x; h_[1] = (_Float16)u.y;                           \
        h_[2] = (_Float16)u.z; h_[3] = (_Float16)u.w;                           \
        h_[4] = (_Float16)v.x; h_[5] = (_Float16)v.y;                           \
        h_[6] = (_Float16)v.z; h_[7] = (_Float16)v.w;                           \
        *(half8*)((base) + (s) * 4096 + awoff) = h_;                            \
    } while (0)

#define B_LOAD(BK, ks)                                                          \
    do {                                                                        \
        const _Float16* bp_ = bptr + (size_t)(ks) * 16384;                      \
        BK[0] = *(const half8*)(bp_);                                           \
        BK[1] = *(const half8*)(bp_ + 512);                                     \
        BK[2] = *(const half8*)(bp_ + 1024);                                    \
        BK[3] = *(const half8*)(bp_ + 1536);                                    \
    } while (0)

#define SUB(T, s, BK)                                                           \
    do {                                                                        \
        const int ks_ = 4 * (T) + (s);                                          \
        char* cb_ = smem + ((T) & 1) * 16384;                                   \
        char* nb_ = smem + (((T) + 1) & 1) * 16384;                             \
        if (w < 4) {                                                            \
            if (ks_ < 28) AV_CVTW(s, nb_);      /* write tile T+1 sub s */      \
            if (ks_ < 24) AV_LOAD(s, ks_ + 8);  /* refill for tile T+2 */       \
        }                                                                       \
        half8 a0 = *(const half8*)(cb_ + (s) * 4096 + 0 * 1024 + lane * 16);    \
        half8 a1 = *(const half8*)(cb_ + (s) * 4096 + 1 * 1024 + lane * 16);    \
        half8 a2 = *(const half8*)(cb_ + (s) * 4096 + 2 * 1024 + lane * 16);    \
        half8 a3 = *(const half8*)(cb_ + (s) * 4096 + 3 * 1024 + lane * 16);    \
        __builtin_amdgcn_s_setprio(1);                                          \
        acc[0][0] = __builtin_amdgcn_mfma_f32_16x16x32_f16(a0, BK[0], acc[0][0], 0, 0, 0); \
        acc[0][1] = __builtin_amdgcn_mfma_f32_16x16x32_f16(a0, BK[1], acc[0][1], 0, 0, 0); \
        acc[0][2] = __builtin_amdgcn_mfma_f32_16x16x32_f16(a0, BK[2], acc[0][2], 0, 0, 0); \
        acc[0][3] = __builtin_amdgcn_mfma_f32_16x16x32_f16(a0, BK[3], acc[0][3], 0, 0, 0); \
        acc[1][0] = __builtin_amdgcn_mfma_f32_16x16x32_f16(a1, BK[0], acc[1][0], 0, 0, 0); \
        acc[1][1] = __builtin_amdgcn_mfma_f32_16x16x32_f16(a1, BK[1], acc[1][1], 0, 0, 0); \
        acc[1][2] = __builtin_amdgcn_mfma_f32_16x16x32_f16(a1, BK[2], acc[1][2], 0, 0, 0); \
        acc[1][3] = __builtin_amdgcn_mfma_f32_16x16x32_f16(a1, BK[3], acc[1][3], 0, 0, 0); \
        acc[2][0] = __builtin_amdgcn_mfma_f32_16x16x32_f16(a2, BK[0], acc[2][0], 0, 0, 0); \
        acc[2][1] = __builtin_amdgcn_mfma_f32_16x16x32_f16(a2, BK[1], acc[2][1], 0, 0, 0); \
        acc[2][2] = __builtin_amdgcn_mfma_f32_16x16x32_f16(a2, BK[2], acc[2][2], 0, 0, 0); \
        acc[2][3] = __builtin_amdgcn_mfma_f32_16x16x32_f16(a2, BK[3], acc[2][3], 0, 0, 0); \
        acc[3][0] = __builtin_amdgcn_mfma_f32_16x16x32_f16(a3, BK[0], acc[3][0], 0, 0, 0); \
        acc[3][1] = __builtin_amdgcn_mfma_f32_16x16x32_f16(a3, BK[1], acc[3][1], 0, 0, 0); \
        acc[3][2] = __builtin_amdgcn_mfma_f32_16x16x32_f16(a3, BK[2], acc[3][2], 0, 0, 0); \
        acc[3][3] = __builtin_amdgcn_mfma_f32_16x16x32_f16(a3, BK[3], acc[3][3], 0, 0, 0); \
        __builtin_amdgcn_s_setprio(0);                                          \
        if (ks_ <= 29) B_LOAD(BK, ks_ + 2);  /* refill consumed bank, 2-deep */ \
        if ((s) == 3) {                                                         \
            asm volatile("s_waitcnt lgkmcnt(0)" ::: "memory");                  \
            __builtin_amdgcn_sched_barrier(0);                                  \
            __builtin_amdgcn_s_barrier();                                       \
        }                                                                       \
    } while (0)

    // ---- prologue: tile0 -> buf0 (waves 0-3); B banks <- ks 0,1 (all) ----
    if (w < 4) { AV_LOAD(0, 0); AV_LOAD(1, 1); AV_LOAD(2, 2); AV_LOAD(3, 3); }
    B_LOAD(bk0, 0); B_LOAD(bk1, 1);
    if (w < 4) {
        AV_CVTW(0, smem); AV_CVTW(1, smem); AV_CVTW(2, smem); AV_CVTW(3, smem);
        AV_LOAD(0, 4); AV_LOAD(1, 5); AV_LOAD(2, 6); AV_LOAD(3, 7);
    }
    asm volatile("s_waitcnt lgkmcnt(0)" ::: "memory");
    __builtin_amdgcn_sched_barrier(0);
    __builtin_amdgcn_s_barrier();

    for (int T = 0; T < 8; ++T) {
        SUB(T, 0, bk0);
        SUB(T, 1, bk1);
        SUB(T, 2, bk0);
        SUB(T, 3, bk1);
    }

    // ---- epilogue: h = acc + b1; gelu; *W2; reduce 512 cols -> scores ----
    __syncthreads();
    float* red = (float*)smem;  // [8][64][17]
    const int hi = lane >> 4, lc = lane & 15;
    float b1v[4], w2v[4];
#pragma unroll
    for (int nf = 0; nf < 4; ++nf) {
        int c = w * 64 + nf * 16 + lc;
        b1v[nf] = b1[c];
        w2v[nf] = W2[c];
    }
#pragma unroll
    for (int mf = 0; mf < 4; ++mf) {
#pragma unroll
        for (int i = 0; i < 4; ++i) {
            float s = 0.f;
#pragma unroll
            for (int nf = 0; nf < 4; ++nf) {
                float h = acc[mf][nf][i] + b1v[nf];
                s = fmaf(gelu_exact(h), w2v[nf], s);
            }
            red[(w * 64 + mf * 16 + hi * 4 + i) * 17 + lc] = s;
        }
    }
    __syncthreads();
    if (t < 64) {
        // bit-identical to old p0 + p1 (nb partial sums): lo = waves 0-3,
        // hi = waves 4-7, each in (ww outer, c inner) order, then one add.
        float s_lo = 0.f, s_hi = 0.f;
#pragma unroll
        for (int ww = 0; ww < 4; ++ww)
#pragma unroll
            for (int c = 0; c < 16; ++c) s_lo += red[(ww * 64 + t) * 17 + c];
#pragma unroll
        for (int ww = 4; ww < 8; ++ww)
#pragma unroll
            for (int c = 0; c < 16; ++c) s_hi += red[(ww * 64 + t) * 17 + c];
        scores[m0 + t] = s_lo + s_hi;
    }
}

// ---- flag + provisional select from screen scores ----
__global__ void flag_select_kernel(const float* __restrict__ scores,
                                   int* __restrict__ sel_buf,
                                   int* __restrict__ flag_list,
                                   int* __restrict__ counter, int N, int nseg_tot) {
    int seg = blockIdx.x * 256 + threadIdx.x;
    if (seg >= nseg_tot) return;
    int b = seg >> 5, s = seg & 31;
    size_t base = (size_t)b * N + s * SEG_LEN;
    float sc[SEG_LEN];
#pragma unroll
    for (int j = 0; j < SEG_LEN; ++j) sc[j] = scores[base + j];
    unsigned mask = 0;
    float best9 = 0.f;
    for (int it = 0; it < QUOTA; ++it) {
        float best = 0.f; int bi = 0; bool found = false;
        for (int i = 0; i < SEG_LEN; ++i) if (!((mask >> i) & 1u)) {
            if (!found || sc[i] > best) { best = sc[i]; bi = i; found = true; }
        }
        mask |= 1u << bi;
        best9 = best;
    }
    float best10 = 0.f; bool f10 = false;
    for (int i = 0; i < SEG_LEN; ++i) if (!((mask >> i) & 1u)) {
        if (!f10 || sc[i] > best10) { best10 = sc[i]; f10 = true; }
    }
    if (best9 - best10 > GAP_THR) {
        int c = 0;
        for (int i = 0; i < SEG_LEN; ++i)
            if ((mask >> i) & 1u) sel_buf[(size_t)seg * QUOTA + (c++)] = i;
    } else {
        int p = atomicAdd(counter, 1);
        flag_list[p] = seg;
    }
}

// ---- exact recheck (fp16-split 3-pass, proven numerics) of flagged segments ----
__global__ __launch_bounds__(512, 2)
void recheck_kernel(const float* __restrict__ X, const _Float16* __restrict__ B32,
                    const float* __restrict__ b1, const float* __restrict__ W2,
                    const int* __restrict__ flag_list, const int* __restrict__ counter,
                    int* __restrict__ sel_buf, int N) {
    const int count = *counter;
    const int jb = blockIdx.x;
    if (jb * 3 >= count) return;
    __shared__ __align__(16) char smem[73728];
    const int t = threadIdx.x, w = t >> 6, lane = t & 63;

    const int r_ = t >> 3, kq8 = t & 7;
    int q = r_ / 18, rr = r_ % 18;
    if (r_ >= 54) { q = 2; rr = 0; }
    int li = jb * 3 + q; if (li >= count) li = count - 1;
    const int sg = flag_list[li];
    const float* aRow = X + ((size_t)(sg >> 5) * N + (sg & 31) * SEG_LEN + rr) * H_DIM + kq8 * 4;
    const int rg = r_ >> 5, aks = kq8 >> 2, ahi = (kq8 >> 1) & 1;
    const int aoff = (rg * 2 + aks) * 1024 + (ahi * 32 + (r_ & 31)) * 16 + (kq8 & 1) * 8;

    f32x16 acc1[2][2] = {};
    f32x16 acc2[2][2] = {};
    float4 av = *(const float4*)aRow;

    for (int kt = 0; kt < 32; ++kt) {
#pragma unroll
        for (int r8 = 0; r8 < 8; ++r8) {
            int idx = r8 * 512 + t;
            gload_lds16(B32 + (size_t)kt * 32768 + (size_t)idx * 8,
                        smem + 8192 + (size_t)idx * 16);
        }
        {
            float xs[4] = {av.x, av.y, av.z, av.w};
            half4 h0, h1;
#pragma unroll
            for (int j = 0; j < 4; ++j) {
                _Float16 a = (_Float16)xs[j];
                float r = xs[j] - (float)a;
                h0[j] = a;
                h1[j] = (_Float16)(r * 2048.0f);
            }
            *(half4*)(smem + aoff) = h0;
            *(half4*)(smem + 4096 + aoff) = h1;
        }
        int ktn = kt < 31 ? kt + 1 : 31;
        av = *(const float4*)(aRow + ktn * 32);
        asm volatile("s_waitcnt vmcnt(1) lgkmcnt(0)" ::: "memory");
        __builtin_amdgcn_sched_barrier(0);
        __builtin_amdgcn_s_barrier();

        half8 a0[4], a1[4], b0[4], b1f[4];
#pragma unroll
        for (int mf = 0; mf < 2; ++mf)
#pragma unroll
            for (int ks2 = 0; ks2 < 2; ++ks2) {
                a0[mf * 2 + ks2] = *(const half8*)(smem + (mf * 2 + ks2) * 1024 + lane * 16);
                a1[mf * 2 + ks2] = *(const half8*)(smem + 4096 + (mf * 2 + ks2) * 1024 + lane * 16);
            }
        const char* bb = smem + 8192 + (w >> 2) * 32768;
#pragma unroll
        for (int nfl = 0; nfl < 2; ++nfl)
#pragma unroll
            for (int ks2 = 0; ks2 < 2; ++ks2) {
                b0[nfl * 2 + ks2]  = *(const half8*)(bb + ks2 * 8192 + ((w & 3) * 2 + nfl) * 1024 + lane * 16);
                b1f[nfl * 2 + ks2] = *(const half8*)(bb + 16384 + ks2 * 8192 + ((w & 3) * 2 + nfl) * 1024 + lane * 16);
            }
        __builtin_amdgcn_s_setprio(1);
#pragma unroll
        for (int mf = 0; mf < 2; ++mf)
#pragma unroll
            for (int nfl = 0; nfl < 2; ++nfl)
#pragma unroll
                for (int ks2 = 0; ks2 < 2; ++ks2)
                    acc1[mf][nfl] = __builtin_amdgcn_mfma_f32_32x32x16_f16(
                        a0[mf * 2 + ks2], b0[nfl * 2 + ks2], acc1[mf][nfl], 0, 0, 0);
#pragma unroll
        for (int mf = 0; mf < 2; ++mf)
#pragma unroll
            for (int nfl = 0; nfl < 2; ++nfl)
#pragma unroll
                for (int ks2 = 0; ks2 < 2; ++ks2)
                    acc2[mf][nfl] = __builtin_amdgcn_mfma_f32_32x32x16_f16(
                        a0[mf * 2 + ks2], b1f[nfl * 2 + ks2], acc2[mf][nfl], 0, 0, 0);
#pragma unroll
        for (int mf = 0; mf < 2; ++mf)
#pragma unroll
            for (int nfl = 0; nfl < 2; ++nfl)
#pragma unroll
                for (int ks2 = 0; ks2 < 2; ++ks2)
                    acc2[mf][nfl] = __builtin_amdgcn_mfma_f32_32x32x16_f16(
                        a1[mf * 2 + ks2], b0[nfl * 2 + ks2], acc2[mf][nfl], 0, 0, 0);
        __builtin_amdgcn_s_setprio(0);
        __builtin_amdgcn_s_barrier();
    }

    __syncthreads();
    float* red = (float*)smem;                 // [8][64][33]
    float b1v[2], w2v[2];
#pragma unroll
    for (int nfl = 0; nfl < 2; ++nfl) {
        int c = (w >> 2) * 256 + ((w & 3) * 2 + nfl) * 32 + (lane & 31);
        b1v[nfl] = b1[c];
        w2v[nfl] = W2[c];
    }
#pragma unroll
    for (int mf = 0; mf < 2; ++mf)
#pragma unroll
        for (int i = 0; i < 16; ++i) {
            float s = 0.f;
#pragma unroll
            for (int nfl = 0; nfl < 2; ++nfl) {
                float h = acc1[mf][nfl][i] + acc2[mf][nfl][i] * (1.0f / 2048.0f) + b1v[nfl];
                s = fmaf(gelu_exact(h), w2v[nfl], s);
            }
            int row = mf * 32 + (i & 3) + 8 * (i >> 2) + 4 * (lane >> 5);
            red[(w * 64 + row) * 33 + (lane & 31)] = s;
        }
    __syncthreads();
    float* sx = (float*)(smem + 67584);        // [64]
    if (t < 64) {
        float s = 0.f;
        for (int ww = 0; ww < 8; ++ww)
#pragma unroll
            for (int lc = 0; lc < 32; ++lc) s += red[(ww * 64 + t) * 33 + lc];
        sx[t] = s;
    }
    __syncthreads();
    if (t < 3 && jb * 3 + t < count) {
        int sg2 = flag_list[jb * 3 + t];
        const float* sv = sx + t * SEG_LEN;
        unsigned mask = 0;
        for (int it = 0; it < QUOTA; ++it) {
            float best = 0.f; int bi = 0; bool found = false;
            for (int i = 0; i < SEG_LEN; ++i) if (!((mask >> i) & 1u)) {
                if (!found || sv[i] > best) { best = sv[i]; bi = i; found = true; }
            }
            mask |= 1u << bi;
        }
        int c = 0;
        for (int i = 0; i < SEG_LEN; ++i)
            if ((mask >> i) & 1u) sel_buf[(size_t)sg2 * QUOTA + (c++)] = i;
    }
}

// ---- final gather of selected rows ----
__global__ void gather_kernel(const float* __restrict__ X, const int* __restrict__ sel_buf,
                              float* __restrict__ out, int N) {
    const int seg = blockIdx.x, b = blockIdx.y, t = threadIdx.x;
    const int* sel = sel_buf + ((size_t)b * N_SEG + seg) * QUOTA;
    const float4* xb = (const float4*)X + ((size_t)b * N + seg * SEG_LEN) * (H_DIM / 4);
    float4* ob = (float4*)out + ((size_t)b * N_SEG * QUOTA + seg * QUOTA) * (H_DIM / 4);
#pragma unroll
    for (int j = 0; j < QUOTA; ++j) {
        int r = sel[j];
        ob[(size_t)j * (H_DIM / 4) + t] = xb[(size_t)r * (H_DIM / 4) + t];
    }
}

extern "C" void kernel_launch(void* const* d_in, const int* in_sizes, int n_in,
                              void* d_out, int out_size, void* d_ws, size_t ws_size,
                              hipStream_t stream) {
    const float* X  = (const float*)d_in[0];
    const float* W1 = (const float*)d_in[1];
    const float* b1 = (const float*)d_in[2];
    const float* W2 = (const float*)d_in[3];
    float* out = (float*)d_out;

    const int Hh = in_sizes[2];                        // 512
    const int H  = Hh * 2;                             // 1024
    const long long TOT = (long long)in_sizes[0] / H;  // 147456 tokens
    const int B = 256;
    const int N = (int)(TOT / B);                      // 576
    const int nseg_tot = B * N_SEG;                    // 8192

    char* ws = (char*)d_ws;
    _Float16* B32 = (_Float16*)(ws + 0);               // 2 MB
    _Float16* B16 = (_Float16*)(ws + 2097152);         // 1 MB
    float* scores = (float*)(ws + 3145728);            // TOT f32
    int* sel_buf  = (int*)(ws + 4325376);              // 8192*9
    int* flag_list= (int*)(ws + 4620288);              // 8192
    int* counter  = (int*)(ws + 4653056);

    hipMemsetAsync(counter, 0, 16, stream);

    hipLaunchKernelGGL(pack_w1_kernel, dim3(512), dim3(256), 0, stream, W1, B32, B16);

    hipLaunchKernelGGL(stage1_kernel, dim3((unsigned)(TOT / 64)), dim3(512), 0, stream,
                       X, B16, b1, W2, scores);

    hipLaunchKernelGGL(flag_select_kernel, dim3((nseg_tot + 255) / 256), dim3(256), 0, stream,
                       scores, sel_buf, flag_list, counter, N, nseg_tot);

    hipLaunchKernelGGL(recheck_kernel, dim3((nseg_tot + 2) / 3), dim3(512), 0, stream,
                       X, B32, b1, W2, flag_list, counter, sel_buf, N);

    hipLaunchKernelGGL(gather_kernel, dim3(N_SEG, B), dim3(256), 0, stream,
                       X, sel_buf, out, N);
}

// Round 16
// 541.785 us; speedup vs baseline: 1.6310x; 1.6310x over previous
//
#include <hip/hip_runtime.h>
#include <math.h>

#define H_DIM 1024
#define SEG_LEN 18
#define N_SEG 32
#define QUOTA 9
#define GAP_THR 8.0e-4f

typedef _Float16 half8 __attribute__((ext_vector_type(8)));
typedef _Float16 half4 __attribute__((ext_vector_type(4)));
typedef float f32x4 __attribute__((ext_vector_type(4)));
typedef float f32x16 __attribute__((ext_vector_type(16)));

__device__ __forceinline__ void gload_lds16(const void* g, void* l) {
    __builtin_amdgcn_global_load_lds((const __attribute__((address_space(1))) uint32_t*)g,
                                     (__attribute__((address_space(3))) uint32_t*)l,
                                     16, 0, 0);
}

__device__ __forceinline__ float gelu_exact(float h) {
    return 0.5f * h * (1.0f + erff(h * 0.70710678118654752f));
}

// ---- pack W1 [512][1024] fp32 into two layouts ----
// B32 (2 MB): 32x32x16-frag order, 2 exact-split fp16 planes (recheck kernel).
// B16 (1 MB): 16x16x32-frag order, plane-0 only (screen kernel):
//   half-off = (ks*32 + nf16)*512 + lane*8 + j   (each frag = 1 KB contiguous)
__global__ void pack_w1_kernel(const float* __restrict__ W1,
                               _Float16* __restrict__ B32,
                               _Float16* __restrict__ B16) {
    const int bid = blockIdx.x, t = threadIdx.x;
    if (bid < 256) {
        int tid = bid * 256 + t;
        int q = tid & 127, n = tid >> 7;
        int kt = q >> 2, ksub = (q >> 1) & 1, hi = q & 1;
        int nb = n >> 8, nf = (n >> 5) & 7, nlo = n & 31;
        const float* src = W1 + (size_t)n * H_DIM + q * 8;
        float4 v0 = *(const float4*)src, v1 = *(const float4*)(src + 4);
        float xs[8] = {v0.x, v0.y, v0.z, v0.w, v1.x, v1.y, v1.z, v1.w};
        half8 h0, h1;
#pragma unroll
        for (int j = 0; j < 8; ++j) {
            _Float16 a = (_Float16)xs[j];
            float r = xs[j] - (float)a;
            h0[j] = a;
            h1[j] = (_Float16)(r * 2048.0f);
        }
        size_t base = (size_t)kt * 32768 + nb * 16384 + ksub * 4096 + nf * 512
                    + (size_t)(hi * 32 + nlo) * 8;
        *(half8*)(B32 + base) = h0;
        *(half8*)(B32 + base + 8192) = h1;
    } else {
        int tid = (bid - 256) * 256 + t;
        int lane = tid & 63, nf = (tid >> 6) & 31, ks = tid >> 11;
        int n = nf * 16 + (lane & 15), k0 = ks * 32 + (lane >> 4) * 8;
        const float* src = W1 + (size_t)n * H_DIM + k0;
        float4 v0 = *(const float4*)src, v1 = *(const float4*)(src + 4);
        float xs[8] = {v0.x, v0.y, v0.z, v0.w, v1.x, v1.y, v1.z, v1.w};
        half8 h0;
#pragma unroll
        for (int j = 0; j < 8; ++j) h0[j] = (_Float16)xs[j];
        *(half8*)(B16 + ((size_t)(ks * 32 + nf)) * 512 + lane * 8) = h0;
    }
}

// ---- stage-1 scorer: merged-nb (64 rows x 512 cols, 8 waves of 64x64) ----
// Identical to R15 EXCEPT launch bounds: (512,2) -> VGPR cap 128, no spill
// (R15's (512,4) pinned 64 VGPR and spilled 952 MB to scratch).
__global__ __launch_bounds__(512, 2)
void stage1_kernel(const float* __restrict__ X, const _Float16* __restrict__ B16,
                   const float* __restrict__ b1, const float* __restrict__ W2,
                   float* __restrict__ scores) {
    __shared__ __align__(16) char smem[34816];  // A dbuf 2x16KB; red[8][64][17] overlays
    const int t = threadIdx.x;          // 0..511
    const int w = t >> 6, lane = t & 63;
    const size_t m0 = (size_t)blockIdx.x * 64;

    // A staging role (threads 0-255 = waves 0-3, R14 mapping verbatim)
    const int arow = (w & 3) * 16 + (t & 15);
    const int aq = (t >> 4) & 3;
    const float* aptr = X + (m0 + arow) * H_DIM + aq * 8;
    const int awoff = (w & 3) * 1024 + ((t & 15) + 16 * aq) * 16;
    // B direct: wave w covers cols w*64..w*64+63 -> frags w*4+j
    const _Float16* bptr = B16 + ((size_t)(w * 4)) * 512 + lane * 8;

    f32x4 acc[4][4] = {};
    float4 av[4][2];
    half8 bk0[4], bk1[4];

#define AV_LOAD(s, ks)                                                          \
    do {                                                                        \
        av[s][0] = *(const float4*)(aptr + (ks) * 32);                          \
        av[s][1] = *(const float4*)(aptr + (ks) * 32 + 4);                      \
    } while (0)

#define AV_CVTW(s, base)                                                        \
    do {                                                                        \
        float4 u = av[s][0], v = av[s][1];                                      \
        half8 h_;                                                               \
        h_[0] = (_Float16)u.x; h_[1] = (_Float16)u.y;                           \
        h_[2] = (_Float16)u.z; h_[3] = (_Float16)u.w;                           \
        h_[4] = (_Float16)v.x; h_[5] = (_Float16)v.y;                           \
        h_[6] = (_Float16)v.z; h_[7] = (_Float16)v.w;                           \
        *(half8*)((base) + (s) * 4096 + awoff) = h_;                            \
    } while (0)

#define B_LOAD(BK, ks)                                                          \
    do {                                                                        \
        const _Float16* bp_ = bptr + (size_t)(ks) * 16384;                      \
        BK[0] = *(const half8*)(bp_);                                           \
        BK[1] = *(const half8*)(bp_ + 512);                                     \
        BK[2] = *(const half8*)(bp_ + 1024);                                    \
        BK[3] = *(const half8*)(bp_ + 1536);                                    \
    } while (0)

#define SUB(T, s, BK)                                                           \
    do {                                                                        \
        const int ks_ = 4 * (T) + (s);                                          \
        char* cb_ = smem + ((T) & 1) * 16384;                                   \
        char* nb_ = smem + (((T) + 1) & 1) * 16384;                             \
        if (w < 4) {                                                            \
            if (ks_ < 28) AV_CVTW(s, nb_);      /* write tile T+1 sub s */      \
            if (ks_ < 24) AV_LOAD(s, ks_ + 8);  /* refill for tile T+2 */       \
        }                                                                       \
        half8 a0 = *(const half8*)(cb_ + (s) * 4096 + 0 * 1024 + lane * 16);    \
        half8 a1 = *(const half8*)(cb_ + (s) * 4096 + 1 * 1024 + lane * 16);    \
        half8 a2 = *(const half8*)(cb_ + (s) * 4096 + 2 * 1024 + lane * 16);    \
        half8 a3 = *(const half8*)(cb_ + (s) * 4096 + 3 * 1024 + lane * 16);    \
        __builtin_amdgcn_s_setprio(1);                                          \
        acc[0][0] = __builtin_amdgcn_mfma_f32_16x16x32_f16(a0, BK[0], acc[0][0], 0, 0, 0); \
        acc[0][1] = __builtin_amdgcn_mfma_f32_16x16x32_f16(a0, BK[1], acc[0][1], 0, 0, 0); \
        acc[0][2] = __builtin_amdgcn_mfma_f32_16x16x32_f16(a0, BK[2], acc[0][2], 0, 0, 0); \
        acc[0][3] = __builtin_amdgcn_mfma_f32_16x16x32_f16(a0, BK[3], acc[0][3], 0, 0, 0); \
        acc[1][0] = __builtin_amdgcn_mfma_f32_16x16x32_f16(a1, BK[0], acc[1][0], 0, 0, 0); \
        acc[1][1] = __builtin_amdgcn_mfma_f32_16x16x32_f16(a1, BK[1], acc[1][1], 0, 0, 0); \
        acc[1][2] = __builtin_amdgcn_mfma_f32_16x16x32_f16(a1, BK[2], acc[1][2], 0, 0, 0); \
        acc[1][3] = __builtin_amdgcn_mfma_f32_16x16x32_f16(a1, BK[3], acc[1][3], 0, 0, 0); \
        acc[2][0] = __builtin_amdgcn_mfma_f32_16x16x32_f16(a2, BK[0], acc[2][0], 0, 0, 0); \
        acc[2][1] = __builtin_amdgcn_mfma_f32_16x16x32_f16(a2, BK[1], acc[2][1], 0, 0, 0); \
        acc[2][2] = __builtin_amdgcn_mfma_f32_16x16x32_f16(a2, BK[2], acc[2][2], 0, 0, 0); \
        acc[2][3] = __builtin_amdgcn_mfma_f32_16x16x32_f16(a2, BK[3], acc[2][3], 0, 0, 0); \
        acc[3][0] = __builtin_amdgcn_mfma_f32_16x16x32_f16(a3, BK[0], acc[3][0], 0, 0, 0); \
        acc[3][1] = __builtin_amdgcn_mfma_f32_16x16x32_f16(a3, BK[1], acc[3][1], 0, 0, 0); \
        acc[3][2] = __builtin_amdgcn_mfma_f32_16x16x32_f16(a3, BK[2], acc[3][2], 0, 0, 0); \
        acc[3][3] = __builtin_amdgcn_mfma_f32_16x16x32_f16(a3, BK[3], acc[3][3], 0, 0, 0); \
        __builtin_amdgcn_s_setprio(0);                                          \
        if (ks_ <= 29) B_LOAD(BK, ks_ + 2);  /* refill consumed bank, 2-deep */ \
        if ((s) == 3) {                                                         \
            asm volatile("s_waitcnt lgkmcnt(0)" ::: "memory");                  \
            __builtin_amdgcn_sched_barrier(0);                                  \
            __builtin_amdgcn_s_barrier();                                       \
        }                                                                       \
    } while (0)

    // ---- prologue: tile0 -> buf0 (waves 0-3); B banks <- ks 0,1 (all) ----
    if (w < 4) { AV_LOAD(0, 0); AV_LOAD(1, 1); AV_LOAD(2, 2); AV_LOAD(3, 3); }
    B_LOAD(bk0, 0); B_LOAD(bk1, 1);
    if (w < 4) {
        AV_CVTW(0, smem); AV_CVTW(1, smem); AV_CVTW(2, smem); AV_CVTW(3, smem);
        AV_LOAD(0, 4); AV_LOAD(1, 5); AV_LOAD(2, 6); AV_LOAD(3, 7);
    }
    asm volatile("s_waitcnt lgkmcnt(0)" ::: "memory");
    __builtin_amdgcn_sched_barrier(0);
    __builtin_amdgcn_s_barrier();

    for (int T = 0; T < 8; ++T) {
        SUB(T, 0, bk0);
        SUB(T, 1, bk1);
        SUB(T, 2, bk0);
        SUB(T, 3, bk1);
    }

    // ---- epilogue: h = acc + b1; gelu; *W2; reduce 512 cols -> scores ----
    __syncthreads();
    float* red = (float*)smem;  // [8][64][17]
    const int hi = lane >> 4, lc = lane & 15;
    float b1v[4], w2v[4];
#pragma unroll
    for (int nf = 0; nf < 4; ++nf) {
        int c = w * 64 + nf * 16 + lc;
        b1v[nf] = b1[c];
        w2v[nf] = W2[c];
    }
#pragma unroll
    for (int mf = 0; mf < 4; ++mf) {
#pragma unroll
        for (int i = 0; i < 4; ++i) {
            float s = 0.f;
#pragma unroll
            for (int nf = 0; nf < 4; ++nf) {
                float h = acc[mf][nf][i] + b1v[nf];
                s = fmaf(gelu_exact(h), w2v[nf], s);
            }
            red[(w * 64 + mf * 16 + hi * 4 + i) * 17 + lc] = s;
        }
    }
    __syncthreads();
    if (t < 64) {
        // bit-identical to old p0 + p1 (nb partial sums): lo = waves 0-3,
        // hi = waves 4-7, each in (ww outer, c inner) order, then one add.
        float s_lo = 0.f, s_hi = 0.f;
#pragma unroll
        for (int ww = 0; ww < 4; ++ww)
#pragma unroll
            for (int c = 0; c < 16; ++c) s_lo += red[(ww * 64 + t) * 17 + c];
#pragma unroll
        for (int ww = 4; ww < 8; ++ww)
#pragma unroll
            for (int c = 0; c < 16; ++c) s_hi += red[(ww * 64 + t) * 17 + c];
        scores[m0 + t] = s_lo + s_hi;
    }
}

// ---- flag + provisional select from screen scores ----
__global__ void flag_select_kernel(const float* __restrict__ scores,
                                   int* __restrict__ sel_buf,
                                   int* __restrict__ flag_list,
                                   int* __restrict__ counter, int N, int nseg_tot) {
    int seg = blockIdx.x * 256 + threadIdx.x;
    if (seg >= nseg_tot) return;
    int b = seg >> 5, s = seg & 31;
    size_t base = (size_t)b * N + s * SEG_LEN;
    float sc[SEG_LEN];
#pragma unroll
    for (int j = 0; j < SEG_LEN; ++j) sc[j] = scores[base + j];
    unsigned mask = 0;
    float best9 = 0.f;
    for (int it = 0; it < QUOTA; ++it) {
        float best = 0.f; int bi = 0; bool found = false;
        for (int i = 0; i < SEG_LEN; ++i) if (!((mask >> i) & 1u)) {
            if (!found || sc[i] > best) { best = sc[i]; bi = i; found = true; }
        }
        mask |= 1u << bi;
        best9 = best;
    }
    float best10 = 0.f; bool f10 = false;
    for (int i = 0; i < SEG_LEN; ++i) if (!((mask >> i) & 1u)) {
        if (!f10 || sc[i] > best10) { best10 = sc[i]; f10 = true; }
    }
    if (best9 - best10 > GAP_THR) {
        int c = 0;
        for (int i = 0; i < SEG_LEN; ++i)
            if ((mask >> i) & 1u) sel_buf[(size_t)seg * QUOTA + (c++)] = i;
    } else {
        int p = atomicAdd(counter, 1);
        flag_list[p] = seg;
    }
}

// ---- exact recheck (fp16-split 3-pass, proven numerics) of flagged segments ----
__global__ __launch_bounds__(512, 2)
void recheck_kernel(const float* __restrict__ X, const _Float16* __restrict__ B32,
                    const float* __restrict__ b1, const float* __restrict__ W2,
                    const int* __restrict__ flag_list, const int* __restrict__ counter,
                    int* __restrict__ sel_buf, int N) {
    const int count = *counter;
    const int jb = blockIdx.x;
    if (jb * 3 >= count) return;
    __shared__ __align__(16) char smem[73728];
    const int t = threadIdx.x, w = t >> 6, lane = t & 63;

    const int r_ = t >> 3, kq8 = t & 7;
    int q = r_ / 18, rr = r_ % 18;
    if (r_ >= 54) { q = 2; rr = 0; }
    int li = jb * 3 + q; if (li >= count) li = count - 1;
    const int sg = flag_list[li];
    const float* aRow = X + ((size_t)(sg >> 5) * N + (sg & 31) * SEG_LEN + rr) * H_DIM + kq8 * 4;
    const int rg = r_ >> 5, aks = kq8 >> 2, ahi = (kq8 >> 1) & 1;
    const int aoff = (rg * 2 + aks) * 1024 + (ahi * 32 + (r_ & 31)) * 16 + (kq8 & 1) * 8;

    f32x16 acc1[2][2] = {};
    f32x16 acc2[2][2] = {};
    float4 av = *(const float4*)aRow;

    for (int kt = 0; kt < 32; ++kt) {
#pragma unroll
        for (int r8 = 0; r8 < 8; ++r8) {
            int idx = r8 * 512 + t;
            gload_lds16(B32 + (size_t)kt * 32768 + (size_t)idx * 8,
                        smem + 8192 + (size_t)idx * 16);
        }
        {
            float xs[4] = {av.x, av.y, av.z, av.w};
            half4 h0, h1;
#pragma unroll
            for (int j = 0; j < 4; ++j) {
                _Float16 a = (_Float16)xs[j];
                float r = xs[j] - (float)a;
                h0[j] = a;
                h1[j] = (_Float16)(r * 2048.0f);
            }
            *(half4*)(smem + aoff) = h0;
            *(half4*)(smem + 4096 + aoff) = h1;
        }
        int ktn = kt < 31 ? kt + 1 : 31;
        av = *(const float4*)(aRow + ktn * 32);
        asm volatile("s_waitcnt vmcnt(1) lgkmcnt(0)" ::: "memory");
        __builtin_amdgcn_sched_barrier(0);
        __builtin_amdgcn_s_barrier();

        half8 a0[4], a1[4], b0[4], b1f[4];
#pragma unroll
        for (int mf = 0; mf < 2; ++mf)
#pragma unroll
            for (int ks2 = 0; ks2 < 2; ++ks2) {
                a0[mf * 2 + ks2] = *(const half8*)(smem + (mf * 2 + ks2) * 1024 + lane * 16);
                a1[mf * 2 + ks2] = *(const half8*)(smem + 4096 + (mf * 2 + ks2) * 1024 + lane * 16);
            }
        const char* bb = smem + 8192 + (w >> 2) * 32768;
#pragma unroll
        for (int nfl = 0; nfl < 2; ++nfl)
#pragma unroll
            for (int ks2 = 0; ks2 < 2; ++ks2) {
                b0[nfl * 2 + ks2]  = *(const half8*)(bb + ks2 * 8192 + ((w & 3) * 2 + nfl) * 1024 + lane * 16);
                b1f[nfl * 2 + ks2] = *(const half8*)(bb + 16384 + ks2 * 8192 + ((w & 3) * 2 + nfl) * 1024 + lane * 16);
            }
        __builtin_amdgcn_s_setprio(1);
#pragma unroll
        for (int mf = 0; mf < 2; ++mf)
#pragma unroll
            for (int nfl = 0; nfl < 2; ++nfl)
#pragma unroll
                for (int ks2 = 0; ks2 < 2; ++ks2)
                    acc1[mf][nfl] = __builtin_amdgcn_mfma_f32_32x32x16_f16(
                        a0[mf * 2 + ks2], b0[nfl * 2 + ks2], acc1[mf][nfl], 0, 0, 0);
#pragma unroll
        for (int mf = 0; mf < 2; ++mf)
#pragma unroll
            for (int nfl = 0; nfl < 2; ++nfl)
#pragma unroll
                for (int ks2 = 0; ks2 < 2; ++ks2)
                    acc2[mf][nfl] = __builtin_amdgcn_mfma_f32_32x32x16_f16(
                        a0[mf * 2 + ks2], b1f[nfl * 2 + ks2], acc2[mf][nfl], 0, 0, 0);
#pragma unroll
        for (int mf = 0; mf < 2; ++mf)
#pragma unroll
            for (int nfl = 0; nfl < 2; ++nfl)
#pragma unroll
                for (int ks2 = 0; ks2 < 2; ++ks2)
                    acc2[mf][nfl] = __builtin_amdgcn_mfma_f32_32x32x16_f16(
                        a1[mf * 2 + ks2], b0[nfl * 2 + ks2], acc2[mf][nfl], 0, 0, 0);
        __builtin_amdgcn_s_setprio(0);
        __builtin_amdgcn_s_barrier();
    }

    __syncthreads();
    float* red = (float*)smem;                 // [8][64][33]
    float b1v[2], w2v[2];
#pragma unroll
    for (int nfl = 0; nfl < 2; ++nfl) {
        int c = (w >> 2) * 256 + ((w & 3) * 2 + nfl) * 32 + (lane & 31);
        b1v[nfl] = b1[c];
        w2v[nfl] = W2[c];
    }
#pragma unroll
    for (int mf = 0; mf < 2; ++mf)
#pragma unroll
        for (int i = 0; i < 16; ++i) {
            float s = 0.f;
#pragma unroll
            for (int nfl = 0; nfl < 2; ++nfl) {
                float h = acc1[mf][nfl][i] + acc2[mf][nfl][i] * (1.0f / 2048.0f) + b1v[nfl];
                s = fmaf(gelu_exact(h), w2v[nfl], s);
            }
            int row = mf * 32 + (i & 3) + 8 * (i >> 2) + 4 * (lane >> 5);
            red[(w * 64 + row) * 33 + (lane & 31)] = s;
        }
    __syncthreads();
    float* sx = (float*)(smem + 67584);        // [64]
    if (t < 64) {
        float s = 0.f;
        for (int ww = 0; ww < 8; ++ww)
#pragma unroll
            for (int lc = 0; lc < 32; ++lc) s += red[(ww * 64 + t) * 33 + lc];
        sx[t] = s;
    }
    __syncthreads();
    if (t < 3 && jb * 3 + t < count) {
        int sg2 = flag_list[jb * 3 + t];
        const float* sv = sx + t * SEG_LEN;
        unsigned mask = 0;
        for (int it = 0; it < QUOTA; ++it) {
            float best = 0.f; int bi = 0; bool found = false;
            for (int i = 0; i < SEG_LEN; ++i) if (!((mask >> i) & 1u)) {
                if (!found || sv[i] > best) { best = sv[i]; bi = i; found = true; }
            }
            mask |= 1u << bi;
        }
        int c = 0;
        for (int i = 0; i < SEG_LEN; ++i)
            if ((mask >> i) & 1u) sel_buf[(size_t)sg2 * QUOTA + (c++)] = i;
    }
}

// ---- final gather of selected rows ----
__global__ void gather_kernel(const float* __restrict__ X, const int* __restrict__ sel_buf,
                              float* __restrict__ out, int N) {
    const int seg = blockIdx.x, b = blockIdx.y, t = threadIdx.x;
    const int* sel = sel_buf + ((size_t)b * N_SEG + seg) * QUOTA;
    const float4* xb = (const float4*)X + ((size_t)b * N + seg * SEG_LEN) * (H_DIM / 4);
    float4* ob = (float4*)out + ((size_t)b * N_SEG * QUOTA + seg * QUOTA) * (H_DIM / 4);
#pragma unroll
    for (int j = 0; j < QUOTA; ++j) {
        int r = sel[j];
        ob[(size_t)j * (H_DIM / 4) + t] = xb[(size_t)r * (H_DIM / 4) + t];
    }
}

extern "C" void kernel_launch(void* const* d_in, const int* in_sizes, int n_in,
                              void* d_out, int out_size, void* d_ws, size_t ws_size,
                              hipStream_t stream) {
    const float* X  = (const float*)d_in[0];
    const float* W1 = (const float*)d_in[1];
    const float* b1 = (const float*)d_in[2];
    const float* W2 = (const float*)d_in[3];
    float* out = (float*)d_out;

    const int Hh = in_sizes[2];                        // 512
    const int H  = Hh * 2;                             // 1024
    const long long TOT = (long long)in_sizes[0] / H;  // 147456 tokens
    const int B = 256;
    const int N = (int)(TOT / B);                      // 576
    const int nseg_tot = B * N_SEG;                    // 8192

    char* ws = (char*)d_ws;
    _Float16* B32 = (_Float16*)(ws + 0);               // 2 MB
    _Float16* B16 = (_Float16*)(ws + 2097152);         // 1 MB
    float* scores = (float*)(ws + 3145728);            // TOT f32
    int* sel_buf  = (int*)(ws + 4325376);              // 8192*9
    int* flag_list= (int*)(ws + 4620288);              // 8192
    int* counter  = (int*)(ws + 4653056);

    hipMemsetAsync(counter, 0, 16, stream);

    hipLaunchKernelGGL(pack_w1_kernel, dim3(512), dim3(256), 0, stream, W1, B32, B16);

    hipLaunchKernelGGL(stage1_kernel, dim3((unsigned)(TOT / 64)), dim3(512), 0, stream,
                       X, B16, b1, W2, scores);

    hipLaunchKernelGGL(flag_select_kernel, dim3((nseg_tot + 255) / 256), dim3(256), 0, stream,
                       scores, sel_buf, flag_list, counter, N, nseg_tot);

    hipLaunchKernelGGL(recheck_kernel, dim3((nseg_tot + 2) / 3), dim3(512), 0, stream,
                       X, B32, b1, W2, flag_list, counter, sel_buf, N);

    hipLaunchKernelGGL(gather_kernel, dim3(N_SEG, B), dim3(256), 0, stream,
                       X, sel_buf, out, N);
}